// Round 1
// baseline (5262.458 us; speedup 1.0000x reference)
//
#include <hip/hip_runtime.h>
#include <math.h>

#define NROWS 16384   // B*S = 8*2048
#define DDIM  256
#define KTOT  6174    // 5832 + 324 + 18
#define ASTRIDE 260   // 256 + 4 pad (floats)
#define BSTRIDE 36    // 32 + 4 pad (floats)

// ---------------- Kernel A: codebook squared norms ----------------
__global__ __launch_bounds__(256) void wsq_kernel(const float* __restrict__ cb0,
                                                  const float* __restrict__ cb1,
                                                  const float* __restrict__ cb2,
                                                  float* __restrict__ wsq) {
    int wave = blockIdx.x * 4 + (threadIdx.x >> 6);
    int lane = threadIdx.x & 63;
    if (wave >= KTOT) return;
    const float* p; int r;
    if (wave < 5832)      { p = cb0; r = wave; }
    else if (wave < 6156) { p = cb1; r = wave - 5832; }
    else                  { p = cb2; r = wave - 6156; }
    float4 v = *reinterpret_cast<const float4*>(p + (size_t)r * DDIM + lane * 4);
    float s = v.x*v.x + v.y*v.y + v.z*v.z + v.w*v.w;
    #pragma unroll
    for (int off = 32; off > 0; off >>= 1) s += __shfl_xor(s, off, 64);
    if (lane == 0) wsq[wave] = s;
}

// ---------------- Kernel B: fused GEMM + argmin -------------------
// block: 64 rows x all K.  A[64][260] full-D in LDS; B double-buffered
// [2][256][36] per 32-d chunk.  Micro-tile: 4 rows (ty+16i) x 16 ks (tx+16j).
__global__ __launch_bounds__(256, 1) void argmin_kernel(
    const float* __restrict__ embeds,
    const float* __restrict__ cb0,
    const float* __restrict__ cb1,
    const float* __restrict__ cb2,
    const float* __restrict__ wsq,
    int* __restrict__ idxout) {
  extern __shared__ float smem[];
  float* As = smem;                         // [64][ASTRIDE]
  float* Bs = smem + 64 * ASTRIDE;          // [2][256][BSTRIDE]

  const int tid = threadIdx.x;
  const int tx  = tid & 15;
  const int ty  = tid >> 4;
  const int m0  = blockIdx.x * 64;

  // Stage A tile once: 64 rows x 256 cols
  #pragma unroll
  for (int p = 0; p < 16; ++p) {
    int q  = tid + 256 * p;
    int r  = q >> 6;
    int dq = q & 63;
    float4 v = *reinterpret_cast<const float4*>(embeds + (size_t)(m0 + r) * DDIM + dq * 4);
    *reinterpret_cast<float4*>(As + r * ASTRIDE + dq * 4) = v;
  }

  const float* cbs[3] = {cb0, cb1, cb2};
  const int    Ks[3]  = {5832, 324, 18};
  const int    wo[3]  = {0, 5832, 6156};

  for (int c3 = 0; c3 < 3; ++c3) {
    const float* __restrict__ cb = cbs[c3];
    const int K = Ks[c3];
    const float* wsqc = wsq + wo[c3];
    float bestv[4] = {INFINITY, INFINITY, INFINITY, INFINITY};
    int   besti[4] = {0, 0, 0, 0};
    const int nt = (K + 255) >> 8;

    for (int kt = 0; kt < nt; ++kt) {
      const int k0 = kt << 8;
      float acc[4][16];
      #pragma unroll
      for (int i = 0; i < 4; ++i)
        #pragma unroll
        for (int j = 0; j < 16; ++j) acc[i][j] = 0.f;

      const int  krow  = k0 + tid;        // this thread stages codebook row 'tid' of the tile
      const bool valid = (krow < K);
      float4 sreg[8];

      // prologue: load chunk 0 (32 floats of own row), sync vs prior tile, write buf0
      if (valid) {
        const float* src = cb + (size_t)krow * DDIM;
        #pragma unroll
        for (int p = 0; p < 8; ++p) sreg[p] = *reinterpret_cast<const float4*>(src + p * 4);
      } else {
        #pragma unroll
        for (int p = 0; p < 8; ++p) sreg[p] = make_float4(0.f, 0.f, 0.f, 0.f);
      }
      __syncthreads();
      {
        float* dst = Bs + tid * BSTRIDE;
        #pragma unroll
        for (int p = 0; p < 8; ++p) *reinterpret_cast<float4*>(dst + p * 4) = sreg[p];
      }

      // wsq fragment for this thread's 16 k's
      float wv[16];
      #pragma unroll
      for (int j = 0; j < 16; ++j) {
        int kk = k0 + tx + 16 * j;
        wv[j] = (kk < K) ? wsqc[kk] : INFINITY;
      }

      for (int c = 0; c < 8; ++c) {
        if (c < 7 && valid) {                 // issue next chunk's global loads early
          const float* src = cb + (size_t)krow * DDIM + (c + 1) * 32;
          #pragma unroll
          for (int p = 0; p < 8; ++p) sreg[p] = *reinterpret_cast<const float4*>(src + p * 4);
        }
        __syncthreads();                      // buf[c&1] fully written
        const float* Bbuf = Bs + (c & 1) * 256 * BSTRIDE;
        #pragma unroll
        for (int dq = 0; dq < 8; ++dq) {
          const int d = c * 32 + dq * 4;
          float4 a[4];
          #pragma unroll
          for (int i = 0; i < 4; ++i)
            a[i] = *reinterpret_cast<const float4*>(As + (ty + 16 * i) * ASTRIDE + d);
          #pragma unroll
          for (int j = 0; j < 16; ++j) {
            float4 b = *reinterpret_cast<const float4*>(Bbuf + (tx + 16 * j) * BSTRIDE + dq * 4);
            #pragma unroll
            for (int i = 0; i < 4; ++i) {
              acc[i][j] = fmaf(a[i].x, b.x, acc[i][j]);
              acc[i][j] = fmaf(a[i].y, b.y, acc[i][j]);
              acc[i][j] = fmaf(a[i].z, b.z, acc[i][j]);
              acc[i][j] = fmaf(a[i].w, b.w, acc[i][j]);
            }
          }
        }
        if (c < 7) {                          // write next chunk late (latency hidden by compute)
          float* dst = Bs + ((c + 1) & 1) * 256 * BSTRIDE + tid * BSTRIDE;
          #pragma unroll
          for (int p = 0; p < 8; ++p) *reinterpret_cast<float4*>(dst + p * 4) = sreg[p];
        }
      }

      // distances + running argmin (first-index wins on ties: ascending scan, strict <)
      #pragma unroll
      for (int j = 0; j < 16; ++j) {
        const int kk = k0 + tx + 16 * j;
        #pragma unroll
        for (int i = 0; i < 4; ++i) {
          float dv = fmaf(-2.f, acc[i][j], wv[j]);
          if (dv < bestv[i]) { bestv[i] = dv; besti[i] = kk; }
        }
      }
    } // kt

    // reduce across the 16 tx-lanes sharing the same rows
    #pragma unroll
    for (int i = 0; i < 4; ++i) {
      float bv = bestv[i]; int bi = besti[i];
      #pragma unroll
      for (int off = 1; off < 16; off <<= 1) {
        float ov = __shfl_xor(bv, off, 16);
        int   oi = __shfl_xor(bi, off, 16);
        if (ov < bv || (ov == bv && oi < bi)) { bv = ov; bi = oi; }
      }
      if (tx == 0) idxout[c3 * NROWS + m0 + ty + 16 * i] = bi;
    }
    __syncthreads();
  } // c3
}

// ---------------- Kernel C: gather + loss partials ----------------
__global__ __launch_bounds__(256) void gather_kernel(
    const float* __restrict__ embeds,
    const float* __restrict__ cb0,
    const float* __restrict__ cb1,
    const float* __restrict__ cb2,
    const int* __restrict__ idx,
    float* __restrict__ out,
    float* __restrict__ partials) {
  const int tid  = threadIdx.x;
  const int wv   = tid >> 6;
  const int lane = tid & 63;
  float s = 0.f;
  for (int pair = blockIdx.x * 4 + wv; pair < 3 * NROWS; pair += gridDim.x * 4) {
    const int l = pair >> 14;
    const int n = pair & (NROWS - 1);
    const float* cb = (l == 0) ? cb0 : ((l == 1) ? cb1 : cb2);
    const int ix = idx[(l << 14) + n];
    float4 q = *reinterpret_cast<const float4*>(cb + (size_t)ix * DDIM + lane * 4);
    float4 e = *reinterpret_cast<const float4*>(embeds + (size_t)n * DDIM + lane * 4);
    *reinterpret_cast<float4*>(out + (size_t)pair * DDIM + lane * 4) = q;
    float dx = q.x - e.x, dy = q.y - e.y, dz = q.z - e.z, dw = q.w - e.w;
    s += dx * dx + dy * dy + dz * dz + dw * dw;
  }
  __shared__ float red[256];
  red[tid] = s;
  __syncthreads();
  for (int st = 128; st > 0; st >>= 1) {
    if (tid < st) red[tid] += red[tid + st];
    __syncthreads();
  }
  if (tid == 0) partials[blockIdx.x] = red[0];
}

// ---------------- Kernel D: final loss reduction ------------------
__global__ __launch_bounds__(256) void reduce_kernel(const float* __restrict__ partials,
                                                     float* __restrict__ out_loss) {
  __shared__ float red[256];
  const int tid = threadIdx.x;
  float s = 0.f;
  for (int i = tid; i < 1024; i += 256) s += partials[i];
  red[tid] = s;
  __syncthreads();
  for (int st = 128; st > 0; st >>= 1) {
    if (tid < st) red[tid] += red[tid + st];
    __syncthreads();
  }
  if (tid == 0) out_loss[0] = red[0] * (1.25f / ((float)NROWS * (float)DDIM));
}

extern "C" void kernel_launch(void* const* d_in, const int* in_sizes, int n_in,
                              void* d_out, int out_size, void* d_ws, size_t ws_size,
                              hipStream_t stream) {
  const float* embeds = (const float*)d_in[0];
  const float* cb0    = (const float*)d_in[1];
  const float* cb1    = (const float*)d_in[2];
  const float* cb2    = (const float*)d_in[3];
  float* out  = (float*)d_out;
  float* loss = out + (size_t)3 * NROWS * DDIM;

  float* wsq      = (float*)d_ws;                        // 6174 floats
  int*   idx      = (int*)((char*)d_ws + 32768);         // 3*16384 ints
  float* partials = (float*)((char*)d_ws + 262144);      // 1024 floats

  (void)in_sizes; (void)n_in; (void)out_size; (void)ws_size;

  hipFuncSetAttribute((const void*)argmin_kernel,
                      hipFuncAttributeMaxDynamicSharedMemorySize, 147456);

  wsq_kernel<<<(KTOT + 3) / 4, 256, 0, stream>>>(cb0, cb1, cb2, wsq);
  const size_t lds = (size_t)(64 * ASTRIDE + 2 * 256 * BSTRIDE) * sizeof(float);
  argmin_kernel<<<256, 256, lds, stream>>>(embeds, cb0, cb1, cb2, wsq, idx);
  gather_kernel<<<1024, 256, 0, stream>>>(embeds, cb0, cb1, cb2, idx, out, partials);
  reduce_kernel<<<1, 256, 0, stream>>>(partials, loss);
}

// Round 2
// 296.508 us; speedup vs baseline: 17.7481x; 17.7481x over previous
//
#include <hip/hip_runtime.h>
#include <math.h>

#define NROWS 16384     // B*S
#define DDIM  256
#define NPAD  6400      // 50 tiles of 128 padded codeword columns
#define NTILES 50
#define L0_END  5832
#define L1_BASE 5888
#define L1_END  6212    // 5888 + 324
#define L2_BASE 6272
#define L2_END  6290    // 6272 + 18

typedef __attribute__((ext_vector_type(8))) short bf16x8;
typedef __attribute__((ext_vector_type(4))) float f32x4;
typedef __attribute__((ext_vector_type(4))) unsigned short us4;

__device__ __forceinline__ unsigned short bf16_rne(float f) {
  unsigned x = __float_as_uint(f);
  unsigned r = x + 0x7fffu + ((x >> 16) & 1u);
  return (unsigned short)(r >> 16);
}
__device__ __forceinline__ float bf16_to_f(unsigned short h) {
  return __uint_as_float(((unsigned)h) << 16);
}

typedef __attribute__((address_space(3))) unsigned int lds_uint;
typedef __attribute__((address_space(1))) const unsigned int glb_uint;
__device__ __forceinline__ void gload16(const void* g, void* l) {
  __builtin_amdgcn_global_load_lds((glb_uint*)g, (lds_uint*)l, 16, 0, 0);
}

__device__ __forceinline__ bool lexless(float av, int ai, float bv, int bi) {
  return (av < bv) || (av == bv && ai < bi);
}
// merge sorted pair (a1<=a2) with sorted pair (b1<=b2) -> new sorted top-2 in a
__device__ __forceinline__ void merge_pair(float& a1, int& a1i, float& a2, int& a2i,
                                           float b1, int b1i, float b2, int b2i) {
  if (lexless(b1, b1i, a1, a1i)) {
    float t1 = a1; int t1i = a1i;
    a1 = b1; a1i = b1i;
    if (lexless(b2, b2i, t1, t1i)) { a2 = b2; a2i = b2i; }
    else                           { a2 = t1; a2i = t1i; }
  } else {
    if (lexless(b1, b1i, a2, a2i)) { a2 = b1; a2i = b1i; }
  }
}

// ---------------- split embeds into bf16 hi/lo ----------------
__global__ __launch_bounds__(256) void split_embeds(const float* __restrict__ e,
                                                    unsigned short* __restrict__ ehi,
                                                    unsigned short* __restrict__ elo) {
  int gid = blockIdx.x * 256 + threadIdx.x;            // 524288 threads, 8 floats each
  const float4* p = reinterpret_cast<const float4*>(e) + (size_t)gid * 2;
  float4 a = p[0], b = p[1];
  float f[8] = {a.x, a.y, a.z, a.w, b.x, b.y, b.z, b.w};
  unsigned short hi[8], lo[8];
  #pragma unroll
  for (int i = 0; i < 8; ++i) {
    hi[i] = bf16_rne(f[i]);
    lo[i] = bf16_rne(f[i] - bf16_to_f(hi[i]));
  }
  us4 h0 = {hi[0], hi[1], hi[2], hi[3]}, h1 = {hi[4], hi[5], hi[6], hi[7]};
  us4 l0 = {lo[0], lo[1], lo[2], lo[3]}, l1 = {lo[4], lo[5], lo[6], lo[7]};
  *reinterpret_cast<us4*>(&ehi[(size_t)gid * 8]) = h0;
  *reinterpret_cast<us4*>(&ehi[(size_t)gid * 8 + 4]) = h1;
  *reinterpret_cast<us4*>(&elo[(size_t)gid * 8]) = l0;
  *reinterpret_cast<us4*>(&elo[(size_t)gid * 8 + 4]) = l1;
}

// ------------- build padded W hi/lo + squared norms -------------
__global__ __launch_bounds__(256) void prep_w(const float* __restrict__ cb0,
                                              const float* __restrict__ cb1,
                                              const float* __restrict__ cb2,
                                              unsigned short* __restrict__ whi,
                                              unsigned short* __restrict__ wlo,
                                              float* __restrict__ wsq) {
  int wv = threadIdx.x >> 6, ln = threadIdx.x & 63;
  int p = blockIdx.x * 4 + wv;                          // 0..6399
  const float* src = nullptr; int local = 0;
  if (p < L0_END)                        { src = cb0; local = p; }
  else if (p >= L1_BASE && p < L1_END)   { src = cb1; local = p - L1_BASE; }
  else if (p >= L2_BASE && p < L2_END)   { src = cb2; local = p - L2_BASE; }
  float4 f = make_float4(0.f, 0.f, 0.f, 0.f);
  if (src) f = *reinterpret_cast<const float4*>(src + (size_t)local * DDIM + ln * 4);
  float v[4] = {f.x, f.y, f.z, f.w};
  unsigned short hi[4], lo[4];
  #pragma unroll
  for (int i = 0; i < 4; ++i) {
    hi[i] = bf16_rne(v[i]);
    lo[i] = bf16_rne(v[i] - bf16_to_f(hi[i]));
  }
  us4 h = {hi[0], hi[1], hi[2], hi[3]}, l = {lo[0], lo[1], lo[2], lo[3]};
  *reinterpret_cast<us4*>(&whi[(size_t)p * DDIM + ln * 4]) = h;
  *reinterpret_cast<us4*>(&wlo[(size_t)p * DDIM + ln * 4]) = l;
  float s = f.x * f.x + f.y * f.y + f.z * f.z + f.w * f.w;
  #pragma unroll
  for (int m = 32; m > 0; m >>= 1) s += __shfl_xor(s, m);
  if (ln == 0) wsq[p] = src ? s : INFINITY;
}

// ------------- MFMA GEMM (K=768 split) + per-tile top-2 -------------
// grid 128 mtiles x 50 ntiles; block 256 = 4 waves (2x2), tile 128x128, BK=32
__global__ __launch_bounds__(256, 2) void gemm_top2(
    const unsigned short* __restrict__ Ehi, const unsigned short* __restrict__ Elo,
    const unsigned short* __restrict__ Whi, const unsigned short* __restrict__ Wlo,
    const float* __restrict__ wsq,
    float2* __restrict__ pv, int2* __restrict__ pi) {
  __shared__ unsigned short As[128 * 32];   // 8 KB, [row][k] stride 32
  __shared__ unsigned short Bs[128 * 32];   // 8 KB, [col][k] stride 32
  __shared__ float4 epi2[2][128];           // 4 KB epilogue merge buffer

  const int tid = threadIdx.x;
  const int wv = tid >> 6, ln = tid & 63;
  const int mt = blockIdx.x & 127, nt = blockIdx.x >> 7;
  const int wm = wv >> 1, wn = wv & 1;
  const int t = ln & 15, g = ln >> 4;

  f32x4 acc[4][4];
  #pragma unroll
  for (int i = 0; i < 4; ++i)
    #pragma unroll
    for (int j = 0; j < 4; ++j) acc[i][j] = (f32x4){0.f, 0.f, 0.f, 0.f};

  for (int s = 0; s < 24; ++s) {
    const int seg = s >> 3;
    const unsigned short* Ab = (seg == 1) ? Elo : Ehi;
    const unsigned short* Bb = (seg == 2) ? Wlo : Whi;
    const int k0 = (s & 7) << 5;
    __syncthreads();                       // everyone done reading prev tile
    #pragma unroll
    for (int c = 0; c < 2; ++c) {
      int e = (wv * 2 + c) * 64 + ln;      // 0..511 16B-chunks
      int row = e >> 2, part = e & 3;
      gload16(Ab + ((size_t)(mt * 128 + row)) * DDIM + k0 + part * 8,
              As + (wv * 2 + c) * 512);
      gload16(Bb + ((size_t)(nt * 128 + row)) * DDIM + k0 + part * 8,
              Bs + (wv * 2 + c) * 512);
    }
    __syncthreads();                       // vmcnt(0) drained -> tile ready
    bf16x8 af[4], bfr[4];
    #pragma unroll
    for (int i = 0; i < 4; ++i)
      af[i] = *reinterpret_cast<const bf16x8*>(&As[(wm * 64 + i * 16 + t) * 32 + g * 8]);
    #pragma unroll
    for (int j = 0; j < 4; ++j)
      bfr[j] = *reinterpret_cast<const bf16x8*>(&Bs[(wn * 64 + j * 16 + t) * 32 + g * 8]);
    #pragma unroll
    for (int i = 0; i < 4; ++i)
      #pragma unroll
      for (int j = 0; j < 4; ++j)
        acc[i][j] = __builtin_amdgcn_mfma_f32_16x16x32_bf16(af[i], bfr[j], acc[i][j], 0, 0, 0);
  }

  // epilogue: dist = wsq - 2*score; per-row top-2 (lexicographic => first-index ties)
  const int colbase = nt * 128 + wn * 64;
  float wq[4];
  #pragma unroll
  for (int j = 0; j < 4; ++j) wq[j] = wsq[colbase + j * 16 + t];

  #pragma unroll
  for (int i = 0; i < 4; ++i) {
    #pragma unroll
    for (int r = 0; r < 4; ++r) {
      float b1 = INFINITY, b2 = INFINITY; int b1i = -1, b2i = -1;
      #pragma unroll
      for (int j = 0; j < 4; ++j) {
        float dv = fmaf(-2.0f, acc[i][j][r], wq[j]);
        int cj = colbase + j * 16 + t;
        if (dv < b1)      { b2 = b1; b2i = b1i; b1 = dv; b1i = cj; }
        else if (dv < b2) { b2 = dv; b2i = cj; }
      }
      #pragma unroll
      for (int m = 1; m < 16; m <<= 1) {
        float o1 = __shfl_xor(b1, m); int o1i = __shfl_xor(b1i, m);
        float o2 = __shfl_xor(b2, m); int o2i = __shfl_xor(b2i, m);
        merge_pair(b1, b1i, b2, b2i, o1, o1i, o2, o2i);
      }
      if (t == 0)
        epi2[wn][wm * 64 + i * 16 + g * 4 + r] =
            make_float4(b1, b2, __int_as_float(b1i), __int_as_float(b2i));
    }
  }
  __syncthreads();
  if (tid < 128) {
    float4 h0 = epi2[0][tid], h1 = epi2[1][tid];
    float a1 = h0.x, a2 = h0.y; int a1i = __float_as_int(h0.z), a2i = __float_as_int(h0.w);
    merge_pair(a1, a1i, a2, a2i, h1.x, __float_as_int(h1.z), h1.y, __float_as_int(h1.w));
    int orow = mt * 128 + tid;
    pv[(size_t)nt * NROWS + orow] = make_float2(a1, a2);
    pi[(size_t)nt * NROWS + orow] = make_int2(a1i, a2i);
  }
}

// ------------- merge per-tile top-2 into per-layer top-2 -------------
__global__ __launch_bounds__(256) void merge_tiles(const float2* __restrict__ pv,
                                                   const int2* __restrict__ pi,
                                                   int2* __restrict__ ci) {
  int gid = blockIdx.x * 256 + threadIdx.x;       // 49152
  int layer = gid >> 14, row = gid & (NROWS - 1);
  int nt0 = (layer == 0) ? 0 : ((layer == 1) ? 46 : 49);
  int nt1 = (layer == 0) ? 46 : ((layer == 1) ? 49 : 50);
  float a1 = INFINITY, a2 = INFINITY; int a1i = -1, a2i = -1;
  for (int nt = nt0; nt < nt1; ++nt) {
    float2 v = pv[(size_t)nt * NROWS + row];
    int2 ix = pi[(size_t)nt * NROWS + row];
    merge_pair(a1, a1i, a2, a2i, v.x, ix.x, v.y, ix.y);
  }
  ci[gid] = make_int2(a1i, a2i);
}

// ------------- exact fp64 rescore + gather + loss partials -------------
__global__ __launch_bounds__(256) void rescore(const float* __restrict__ embeds,
                                               const float* __restrict__ cb0,
                                               const float* __restrict__ cb1,
                                               const float* __restrict__ cb2,
                                               const int2* __restrict__ ci,
                                               float* __restrict__ out,
                                               float* __restrict__ lossp) {
  const int wv = threadIdx.x >> 6, ln = threadIdx.x & 63;
  const int gid = blockIdx.x * 4 + wv;            // 0..49151
  const int layer = gid >> 14, row = gid & (NROWS - 1);
  const float* cb = (layer == 0) ? cb0 : ((layer == 1) ? cb1 : cb2);
  const int base = (layer == 0) ? 0 : ((layer == 1) ? L1_BASE : L2_BASE);
  int2 c = ci[gid];
  int k1 = c.x - base, k2 = c.y - base;
  float4 e = *reinterpret_cast<const float4*>(embeds + (size_t)row * DDIM + ln * 4);
  float4 w1 = *reinterpret_cast<const float4*>(cb + (size_t)k1 * DDIM + ln * 4);
  float4 w2 = *reinterpret_cast<const float4*>(cb + (size_t)k2 * DDIM + ln * 4);
  double d1, d2;
  {
    double x0 = (double)e.x - (double)w1.x, x1 = (double)e.y - (double)w1.y;
    double x2 = (double)e.z - (double)w1.z, x3 = (double)e.w - (double)w1.w;
    d1 = x0 * x0 + x1 * x1 + x2 * x2 + x3 * x3;
    double y0 = (double)e.x - (double)w2.x, y1 = (double)e.y - (double)w2.y;
    double y2 = (double)e.z - (double)w2.z, y3 = (double)e.w - (double)w2.w;
    d2 = y0 * y0 + y1 * y1 + y2 * y2 + y3 * y3;
  }
  #pragma unroll
  for (int m = 32; m > 0; m >>= 1) {
    d1 += __shfl_xor(d1, m);
    d2 += __shfl_xor(d2, m);
  }
  bool first = (d1 < d2) || (d1 == d2 && k1 < k2);
  float4 q = first ? w1 : w2;
  *reinterpret_cast<float4*>(out + (size_t)gid * DDIM + ln * 4) = q;
  float dw = (float)(first ? d1 : d2);
  __shared__ float red[4];
  if (ln == 0) red[wv] = dw;
  __syncthreads();
  if (threadIdx.x == 0) lossp[blockIdx.x] = red[0] + red[1] + red[2] + red[3];
}

__global__ __launch_bounds__(256) void loss_reduce(const float* __restrict__ lossp,
                                                   float* __restrict__ outloss) {
  __shared__ float red[256];
  const int tid = threadIdx.x;
  float s = 0.f;
  for (int i = tid; i < 12288; i += 256) s += lossp[i];
  red[tid] = s;
  __syncthreads();
  for (int st = 128; st > 0; st >>= 1) {
    if (tid < st) red[tid] += red[tid + st];
    __syncthreads();
  }
  if (tid == 0) outloss[0] = red[0] * (1.25f / ((float)NROWS * (float)DDIM));
}

extern "C" void kernel_launch(void* const* d_in, const int* in_sizes, int n_in,
                              void* d_out, int out_size, void* d_ws, size_t ws_size,
                              hipStream_t stream) {
  const float* embeds = (const float*)d_in[0];
  const float* cb0    = (const float*)d_in[1];
  const float* cb1    = (const float*)d_in[2];
  const float* cb2    = (const float*)d_in[3];
  float* out  = (float*)d_out;
  float* loss = out + (size_t)3 * NROWS * DDIM;

  char* ws = (char*)d_ws;
  unsigned short* Ehi = (unsigned short*)(ws);                       // 8,388,608 B
  unsigned short* Elo = (unsigned short*)(ws + 8388608);             // 8,388,608 B
  unsigned short* Whi = (unsigned short*)(ws + 16777216);            // 3,276,800 B
  unsigned short* Wlo = (unsigned short*)(ws + 20054016);            // 3,276,800 B
  float*          wsq = (float*)(ws + 23330816);                     //    25,600 B
  float2*         pv  = (float2*)(ws + 23356416);                    // 6,553,600 B
  int2*           pi  = (int2*)(ws + 29910016);                      // 6,553,600 B
  int2*           ci  = (int2*)(ws + 36463616);                      //   393,216 B
  float*          lp  = (float*)(ws + 36856832);                     //    49,152 B

  (void)in_sizes; (void)n_in; (void)out_size; (void)ws_size;

  split_embeds<<<2048, 256, 0, stream>>>(embeds, Ehi, Elo);
  prep_w<<<1600, 256, 0, stream>>>(cb0, cb1, cb2, Whi, Wlo, wsq);
  gemm_top2<<<128 * NTILES, 256, 0, stream>>>(Ehi, Elo, Whi, Wlo, wsq, pv, pi);
  merge_tiles<<<192, 256, 0, stream>>>(pv, pi, ci);
  rescore<<<12288, 256, 0, stream>>>(embeds, cb0, cb1, cb2, ci, out, lp);
  loss_reduce<<<1, 256, 0, stream>>>(lp, loss);
}